// Round 8
// baseline (1009.624 us; speedup 1.0000x reference)
//
#include <hip/hip_runtime.h>
#include <cstddef>

// Shapes: B=128, T=256, H=128, 4H=512, D=2E=128, GENOME=1e6, OUT*T=256
// d_out: out[128][256] (32768 f32) then emb[128][256][128] (4194304 f32)
// ws (floats): xg @0 (16777216) | hs @16777216 (4194304) | wf_hi @20971520 (32768)
//              | wf_lo @21004288 (32768) | partials @21037056 (1048576)

typedef __attribute__((ext_vector_type(8))) _Float16 f16x8;
typedef __attribute__((ext_vector_type(4))) float f32x4;

__device__ __forceinline__ float frcp(float x) { return __builtin_amdgcn_rcpf(x); }
__device__ __forceinline__ float sigm(float x) { return frcp(1.0f + __expf(-x)); }
__device__ __forceinline__ float ftanh(float x) {
  float e = __expf(2.0f * x);
  return (e - 1.0f) * frcp(e + 1.0f);
}
// split x into fp16 hi + fp16 lo (lo pre-scaled by 2^11)
__device__ __forceinline__ void split2(float x, unsigned short& hi, unsigned short& lo) {
  _Float16 h = (_Float16)x;
  _Float16 l = (_Float16)((x - (float)h) * 2048.0f);
  hi = *(unsigned short*)&h;
  lo = *(unsigned short*)&l;
}
// LDS-only barrier: does NOT drain vmcnt (keeps global prefetch/stores in flight)
__device__ __forceinline__ void barrier_lds() {
  asm volatile("s_waitcnt lgkmcnt(0)\n\ts_barrier" ::: "memory");
}

// ---------- embedding gather ----------
__global__ void k_embed(const int* __restrict__ idx, const float4* __restrict__ table4,
                        float4* __restrict__ emb4) {
  int i = blockIdx.x * blockDim.x + threadIdx.x;   // B*T*2*16 = 1,048,576
  int p = i >> 4, j = i & 15;
  int id = idx[p];
  emb4[(size_t)p * 16 + j] = table4[(size_t)id * 16 + j];
}

// ---------- generic C[M,N] = A[M,K] @ B[N,K]^T, 64x64 tile ----------
__global__ __launch_bounds__(256) void k_gemm_tn(
    const float* __restrict__ A, const float* __restrict__ Bm, float* __restrict__ C,
    int K, int kchunks, int N, size_t partstride)
{
  __shared__ float As[64][65];
  __shared__ float Bs[64][68];
  const int tid = threadIdx.x;
  const int tx = tid & 15, ty = tid >> 4;
  const int m0 = blockIdx.x * 64, n0 = blockIdx.y * 64;
  float acc[4][4] = {};
  size_t kbase = (size_t)blockIdx.z * kchunks * 64;
  for (int kc = 0; kc < kchunks; ++kc) {
    size_t k0 = kbase + (size_t)kc * 64;
    #pragma unroll
    for (int it = 0; it < 4; ++it) {
      int fi = it * 256 + tid;
      int row = fi >> 4, col4 = fi & 15;
      float4 va = *(const float4*)(A + (size_t)(m0 + row) * K + k0 + col4 * 4);
      As[row][col4*4+0] = va.x; As[row][col4*4+1] = va.y;
      As[row][col4*4+2] = va.z; As[row][col4*4+3] = va.w;
      float4 vb = *(const float4*)(Bm + (size_t)(n0 + row) * K + k0 + col4 * 4);
      Bs[col4*4+0][row] = vb.x; Bs[col4*4+1][row] = vb.y;
      Bs[col4*4+2][row] = vb.z; Bs[col4*4+3][row] = vb.w;
    }
    __syncthreads();
    #pragma unroll 8
    for (int k = 0; k < 64; ++k) {
      float a0 = As[ty*4+0][k], a1 = As[ty*4+1][k], a2 = As[ty*4+2][k], a3 = As[ty*4+3][k];
      float b0 = Bs[k][tx*4+0], b1 = Bs[k][tx*4+1], b2 = Bs[k][tx*4+2], b3 = Bs[k][tx*4+3];
      acc[0][0] += a0*b0; acc[0][1] += a0*b1; acc[0][2] += a0*b2; acc[0][3] += a0*b3;
      acc[1][0] += a1*b0; acc[1][1] += a1*b1; acc[1][2] += a1*b2; acc[1][3] += a1*b3;
      acc[2][0] += a2*b0; acc[2][1] += a2*b1; acc[2][2] += a2*b2; acc[2][3] += a2*b3;
      acc[3][0] += a3*b0; acc[3][1] += a3*b1; acc[3][2] += a3*b2; acc[3][3] += a3*b3;
    }
    __syncthreads();
  }
  float* Cp = C + (size_t)blockIdx.z * partstride;
  #pragma unroll
  for (int i = 0; i < 4; ++i) {
    float4 v = make_float4(acc[i][0], acc[i][1], acc[i][2], acc[i][3]);
    *(float4*)(Cp + (size_t)(m0 + ty*4 + i) * N + n0 + tx*4) = v;
  }
}

// ---------- xg := LN(xg)*g_ih + (b_ih + b_hh), in place, one wave per row ----------
__global__ __launch_bounds__(256) void k_xln(float4* __restrict__ xg4,
                                             const float4* __restrict__ g4,
                                             const float4* __restrict__ bi4,
                                             const float4* __restrict__ bh4) {
  int row = blockIdx.x * 4 + (threadIdx.x >> 6);   // 32768 rows
  int lane = threadIdx.x & 63;
  float4* r = xg4 + (size_t)row * 128;
  float4 a = r[lane], b = r[lane + 64];
  float s = a.x + a.y + a.z + a.w + b.x + b.y + b.z + b.w;
  float q = a.x*a.x + a.y*a.y + a.z*a.z + a.w*a.w + b.x*b.x + b.y*b.y + b.z*b.z + b.w*b.w;
  #pragma unroll
  for (int off = 32; off; off >>= 1) { s += __shfl_xor(s, off); q += __shfl_xor(q, off); }
  float m = s * (1.0f / 512.0f);
  float rs = rsqrtf(q * (1.0f / 512.0f) - m * m + 1e-5f);
  float4 ga = g4[lane], gb = g4[64 + lane];
  float4 ia = bi4[lane], ib = bi4[64 + lane];
  float4 ha = bh4[lane], hb = bh4[64 + lane];
  a.x = (a.x - m) * rs * ga.x + ia.x + ha.x; a.y = (a.y - m) * rs * ga.y + ia.y + ha.y;
  a.z = (a.z - m) * rs * ga.z + ia.z + ha.z; a.w = (a.w - m) * rs * ga.w + ia.w + ha.w;
  b.x = (b.x - m) * rs * gb.x + ib.x + hb.x; b.y = (b.y - m) * rs * gb.y + ib.y + hb.y;
  b.z = (b.z - m) * rs * gb.z + ib.z + hb.z; b.w = (b.w - m) * rs * gb.w + ib.w + hb.w;
  r[lane] = a; r[lane + 64] = b;
}

// ---------- W_hh -> dual fp16 A-fragments (hi + scaled lo), k = kc*32+8*(l>>4)+i ----------
__global__ void k_wprep(const float* __restrict__ Whh, uint4* __restrict__ wfh,
                        uint4* __restrict__ wfl) {
  int i = blockIdx.x * 256 + threadIdx.x;  // 8192 = 32*4*64
  int l = i & 63, kc = (i >> 6) & 3, mt = i >> 8;
  int row = mt * 16 + (l & 15);
  int kb = kc * 32 + 8 * (l >> 4);
  float4 a = *(const float4*)(Whh + row * 128 + kb);
  float4 c = *(const float4*)(Whh + row * 128 + kb + 4);
  unsigned short h0,h1,h2,h3,h4,h5,h6,h7, l0,l1,l2,l3,l4,l5,l6,l7;
  split2(a.x,h0,l0); split2(a.y,h1,l1); split2(a.z,h2,l2); split2(a.w,h3,l3);
  split2(c.x,h4,l4); split2(c.y,h5,l5); split2(c.z,h6,l6); split2(c.w,h7,l7);
  uint4 oh, ol;
  oh.x = h0 | ((unsigned)h1 << 16); oh.y = h2 | ((unsigned)h3 << 16);
  oh.z = h4 | ((unsigned)h5 << 16); oh.w = h6 | ((unsigned)h7 << 16);
  ol.x = l0 | ((unsigned)l1 << 16); ol.y = l2 | ((unsigned)l3 << 16);
  ol.z = l4 | ((unsigned)l5 << 16); ol.w = l6 | ((unsigned)l7 << 16);
  wfh[i] = oh; wfl[i] = ol;
}

// ---------- MFMA LSTM scan: 4 batch rows/block (MFMA cols 0-3), 32 blocks, 8 waves.
// W frags pinned in AGPRs; i/f/g/o of each hidden unit land on one lane -> register tail.
__global__ __launch_bounds__(512, 2) void k_scan(
    const float* __restrict__ xln,   // [B][T][512]  (LN(x)*g_ih + b_ih + b_hh)
    const uint4* __restrict__ wfh,   // [32][4][64] A-frags f16 hi
    const uint4* __restrict__ wfl,   // [32][4][64] A-frags f16 lo (x2048)
    const float* __restrict__ h0, const float* __restrict__ c0,
    const float* __restrict__ g_hh,
    const float* __restrict__ g_c,  const float* __restrict__ b_c,
    float* __restrict__ hs)          // [B][T][128]
{
  const int bid = blockIdx.x;            // 32 blocks x 4 batch rows
  const int tid = threadIdx.x;
  const int w = tid >> 6, l = tid & 63;
  const int lg = l >> 4;                 // k-subgroup / C-row-group
  const int col = l & 15;                // MFMA column = batch-row slot
  const bool act = col < 4;              // only cols 0-3 carry real rows
  const int rclamp = act ? col : 0;
  const int row = bid * 4 + rclamp;      // this lane's batch row (clamped)
  const int u0 = 16 * w + 4 * lg;        // this lane's 4 hidden units u0..u0+3
  const float inv2048 = 1.0f / 2048.0f;

  // h storage: 16 sub-tiles of [16 cols][8 fp16]; B-frag read = 16B at kc*1024 + l*16
  __shared__ alignas(16) unsigned short hsth[2048];   // 4 KB hi
  __shared__ alignas(16) unsigned short hstl[2048];   // 4 KB lo
  __shared__ float2 hred[8][16];                      // per-wave LN-h partials per col
  __shared__ float2 cred[8][16];                      // per-wave c partials per col

  // ---- W fragments: load once, PIN IN AGPRs (asm output can't be rematerialized) ----
  const f16x8* wh8 = (const f16x8*)wfh;
  const f16x8* wl8 = (const f16x8*)wfl;
  f16x8 AH0[4], AH1[4], AH2[4], AH3[4], AL0[4], AL1[4], AL2[4], AL3[4];
  #pragma unroll
  for (int kc = 0; kc < 4; ++kc) {
    AH0[kc] = wh8[((w     ) * 4 + kc) * 64 + l];
    AH1[kc] = wh8[((w +  8) * 4 + kc) * 64 + l];
    AH2[kc] = wh8[((w + 16) * 4 + kc) * 64 + l];
    AH3[kc] = wh8[((w + 24) * 4 + kc) * 64 + l];
    AL0[kc] = wl8[((w     ) * 4 + kc) * 64 + l];
    AL1[kc] = wl8[((w +  8) * 4 + kc) * 64 + l];
    AL2[kc] = wl8[((w + 16) * 4 + kc) * 64 + l];
    AL3[kc] = wl8[((w + 24) * 4 + kc) * 64 + l];
  }
  #pragma unroll
  for (int kc = 0; kc < 4; ++kc) {
    asm volatile("" : "+a"(AH0[kc]), "+a"(AH1[kc]), "+a"(AH2[kc]), "+a"(AH3[kc]));
    asm volatile("" : "+a"(AL0[kc]), "+a"(AL1[kc]), "+a"(AL2[kc]), "+a"(AL3[kc]));
  }

  // tail params for this lane's 4 units
  const f32x4 ghI = *(const f32x4*)(g_hh + u0);
  const f32x4 ghF = *(const f32x4*)(g_hh + 128 + u0);
  const f32x4 ghG = *(const f32x4*)(g_hh + 256 + u0);
  const f32x4 ghO = *(const f32x4*)(g_hh + 384 + u0);
  const f32x4 gc4 = *(const f32x4*)(g_c + u0);
  const f32x4 bc4 = *(const f32x4*)(b_c + u0);
  f32x4 cv = *(const f32x4*)(c0 + (size_t)row * 128 + u0);

  // init h store: zero all, then write h0 for cols 0-3 (each (u,col) has one writer)
  #pragma unroll
  for (int i = tid; i < 1024; i += 512) {
    ((unsigned int*)hsth)[i] = 0u;
    ((unsigned int*)hstl)[i] = 0u;
  }
  const int kcb = u0 >> 5, lg2 = (u0 >> 3) & 3, i0 = u0 & 7;
  const int wroff = kcb * 1024 + (lg2 * 16 + col) * 16 + i0 * 2;  // byte offset
  __syncthreads();
  if (act) {
    f32x4 h04 = *(const f32x4*)(h0 + (size_t)row * 128 + u0);
    unsigned short a_, b_, c_, d_, e_, f_, g_, i_;
    split2(h04[0], a_, b_); split2(h04[1], c_, d_);
    split2(h04[2], e_, f_); split2(h04[3], g_, i_);
    uint2 hv; hv.x = (unsigned)a_ | ((unsigned)c_ << 16); hv.y = (unsigned)e_ | ((unsigned)g_ << 16);
    uint2 lv; lv.x = (unsigned)b_ | ((unsigned)d_ << 16); lv.y = (unsigned)f_ | ((unsigned)i_ << 16);
    *(uint2*)((char*)hsth + wroff) = hv;
    *(uint2*)((char*)hstl + wroff) = lv;
  }
  __syncthreads();

  const float* xgb = xln + (size_t)row * 131072;
  float* hsb = hs + (size_t)row * 32768;

  // x prefetch for t=0
  f32x4 xI = *(const f32x4*)(xgb + u0);
  f32x4 xF = *(const f32x4*)(xgb + 128 + u0);
  f32x4 xG = *(const f32x4*)(xgb + 256 + u0);
  f32x4 xO = *(const f32x4*)(xgb + 384 + u0);

  for (int t = 0; t < 256; ++t) {
    // ---- MFMA matvec for 4 batch rows (cols 0-3) ----
    f32x4 acc0 = {0,0,0,0}, acc1 = {0,0,0,0}, acc2 = {0,0,0,0}, acc3 = {0,0,0,0};
    f32x4 e0 = {0,0,0,0}, e1 = {0,0,0,0}, e2 = {0,0,0,0}, e3 = {0,0,0,0};
    #pragma unroll
    for (int kc = 0; kc < 4; ++kc) {
      f16x8 bh = *(const f16x8*)((const char*)hsth + kc * 1024 + l * 16);
      f16x8 bl = *(const f16x8*)((const char*)hstl + kc * 1024 + l * 16);
      acc0 = __builtin_amdgcn_mfma_f32_16x16x32_f16(AH0[kc], bh, acc0, 0, 0, 0);
      acc1 = __builtin_amdgcn_mfma_f32_16x16x32_f16(AH1[kc], bh, acc1, 0, 0, 0);
      acc2 = __builtin_amdgcn_mfma_f32_16x16x32_f16(AH2[kc], bh, acc2, 0, 0, 0);
      acc3 = __builtin_amdgcn_mfma_f32_16x16x32_f16(AH3[kc], bh, acc3, 0, 0, 0);
      e0 = __builtin_amdgcn_mfma_f32_16x16x32_f16(AH0[kc], bl, e0, 0, 0, 0);
      e1 = __builtin_amdgcn_mfma_f32_16x16x32_f16(AH1[kc], bl, e1, 0, 0, 0);
      e2 = __builtin_amdgcn_mfma_f32_16x16x32_f16(AH2[kc], bl, e2, 0, 0, 0);
      e3 = __builtin_amdgcn_mfma_f32_16x16x32_f16(AH3[kc], bl, e3, 0, 0, 0);
      e0 = __builtin_amdgcn_mfma_f32_16x16x32_f16(AL0[kc], bh, e0, 0, 0, 0);
      e1 = __builtin_amdgcn_mfma_f32_16x16x32_f16(AL1[kc], bh, e1, 0, 0, 0);
      e2 = __builtin_amdgcn_mfma_f32_16x16x32_f16(AL2[kc], bh, e2, 0, 0, 0);
      e3 = __builtin_amdgcn_mfma_f32_16x16x32_f16(AL3[kc], bh, e3, 0, 0, 0);
    }
    f32x4 a0, a1, a2, a3;                 // a0=i, a1=f, a2=g, a3=o rows for units u0..u0+3
    #pragma unroll
    for (int j = 0; j < 4; ++j) {
      a0[j] = acc0[j] + e0[j] * inv2048;
      a1[j] = acc1[j] + e1[j] * inv2048;
      a2[j] = acc2[j] + e2[j] * inv2048;
      a3[j] = acc3[j] + e3[j] * inv2048;
    }

    // ---- LN-h stats per batch row (= per col): 16 values/lane, reduce over lg groups ----
    float s = 0.f, q = 0.f;
    #pragma unroll
    for (int j = 0; j < 4; ++j) {
      s += a0[j] + a1[j] + a2[j] + a3[j];
      q += a0[j]*a0[j] + a1[j]*a1[j] + a2[j]*a2[j] + a3[j]*a3[j];
    }
    s += __shfl_xor(s, 16); s += __shfl_xor(s, 32);
    q += __shfl_xor(q, 16); q += __shfl_xor(q, 32);
    if (l < 4) hred[w][l] = make_float2(s, q);

    barrier_lds();                        // B1: hred ready

    float rsx = 0.f, rsq = 0.f;
    #pragma unroll
    for (int w2 = 0; w2 < 8; ++w2) { float2 v = hred[w2][col]; rsx += v.x; rsq += v.y; }
    float mh = rsx * (1.0f / 512.0f);
    float rh = rsqrtf(rsq * (1.0f / 512.0f) - mh * mh + 1e-5f);

    // ---- gates + c update, fully in-register (4 units for this lane's row) ----
    f32x4 cn;
    float cs = 0.f, cq = 0.f;
    #pragma unroll
    for (int j = 0; j < 4; ++j) {
      float gI = xI[j] + (a0[j] - mh) * rh * ghI[j];
      float gF = xF[j] + (a1[j] - mh) * rh * ghF[j];
      float gG = xG[j] + (a2[j] - mh) * rh * ghG[j];
      float gO = xO[j] + (a3[j] - mh) * rh * ghO[j];
      float c_ = sigm(gF) * cv[j] + sigm(gI) * ftanh(gG);
      cn[j] = c_; cv[j] = c_;
      xO[j] = gO;                         // stash o-gate preact for after B2
      cs += c_; cq += c_ * c_;
    }
    cs += __shfl_xor(cs, 16); cs += __shfl_xor(cs, 32);
    cq += __shfl_xor(cq, 16); cq += __shfl_xor(cq, 32);
    if (l < 4) cred[w][l] = make_float2(cs, cq);

    barrier_lds();                        // B2: cred ready

    float tcs = 0.f, tcq = 0.f;
    #pragma unroll
    for (int w2 = 0; w2 < 8; ++w2) { float2 v = cred[w2][col]; tcs += v.x; tcq += v.y; }
    float mc = tcs * (1.0f / 128.0f);
    float rc = rsqrtf(tcq * (1.0f / 128.0f) - mc * mc + 1e-5f);

    f32x4 hn;
    #pragma unroll
    for (int j = 0; j < 4; ++j)
      hn[j] = sigm(xO[j]) * ftanh((cn[j] - mc) * rc * gc4[j] + bc4[j]);

    // ---- publish h (single writer per (unit,col)) + global hs; prefetch next x ----
    if (act) {
      unsigned short a_, b_, c_, d_, e_, f_, g_, i_;
      split2(hn[0], a_, b_); split2(hn[1], c_, d_);
      split2(hn[2], e_, f_); split2(hn[3], g_, i_);
      uint2 hv; hv.x = (unsigned)a_ | ((unsigned)c_ << 16); hv.y = (unsigned)e_ | ((unsigned)g_ << 16);
      uint2 lv; lv.x = (unsigned)b_ | ((unsigned)d_ << 16); lv.y = (unsigned)f_ | ((unsigned)i_ << 16);
      *(uint2*)((char*)hsth + wroff) = hv;
      *(uint2*)((char*)hstl + wroff) = lv;
      *(f32x4*)(hsb + (size_t)t * 128 + u0) = hn;   // fire-and-forget
    }
    const float* xn = xgb + (size_t)((t + 1) & 255) * 512;
    xI = *(const f32x4*)(xn + u0);
    xF = *(const f32x4*)(xn + 128 + u0);
    xG = *(const f32x4*)(xn + 256 + u0);
    xO = *(const f32x4*)(xn + 384 + u0);

    barrier_lds();                        // B3: h visible for next step's MFMA
  }
}

// ---------- k-split reduce + bias + sigmoid ----------
__global__ void k_reduce(const float* __restrict__ part, const float* __restrict__ b_out,
                         float* __restrict__ out) {
  int i = blockIdx.x * 256 + threadIdx.x;   // 0..32767 = b*256+o
  float s = b_out[i & 255];
  #pragma unroll
  for (int z = 0; z < 32; ++z) s += part[(size_t)z * 32768 + i];
  out[i] = sigm(s);
}

extern "C" void kernel_launch(void* const* d_in, const int* in_sizes, int n_in,
                              void* d_out, int out_size, void* d_ws, size_t ws_size,
                              hipStream_t stream) {
  const int*   idx   = (const int*)  d_in[0];
  const float* h0    = (const float*)d_in[1];
  const float* c0    = (const float*)d_in[2];
  const float* table = (const float*)d_in[3];
  const float* W_ih  = (const float*)d_in[4];
  const float* W_hh  = (const float*)d_in[5];
  const float* g_ih  = (const float*)d_in[6];
  const float* b_ih  = (const float*)d_in[7];
  const float* g_hh  = (const float*)d_in[8];
  const float* b_hh  = (const float*)d_in[9];
  const float* g_c   = (const float*)d_in[10];
  const float* b_c   = (const float*)d_in[11];
  const float* W_out = (const float*)d_in[12];
  const float* b_out = (const float*)d_in[13];

  float* out  = (float*)d_out;             // 32768
  float* emb  = out + 32768;               // 4194304 (output #2)
  float* ws   = (float*)d_ws;
  float* xg   = ws;                        // 16777216 floats (becomes xln in place)
  float* hsb  = ws + 16777216;             // 4194304
  uint4* wfh  = (uint4*)(ws + 20971520);   // 8192 uint4 (128 KB)
  uint4* wfl  = (uint4*)(ws + 21004288);   // 8192 uint4 (128 KB)
  float* part = ws + 21037056;             // 1048576

  k_embed<<<4096, 256, 0, stream>>>(idx, (const float4*)table, (float4*)emb);
  // x_gates[32768,512] = emb[32768,128] @ W_ih[512,128]^T
  k_gemm_tn<<<dim3(512, 8, 1), 256, 0, stream>>>(emb, W_ih, xg, 128, 2, 512, 0);
  k_xln<<<8192, 256, 0, stream>>>((float4*)xg, (const float4*)g_ih,
                                  (const float4*)b_ih, (const float4*)b_hh);
  k_wprep<<<32, 256, 0, stream>>>(W_hh, wfh, wfl);
  k_scan<<<32, 512, 0, stream>>>(xg, wfh, wfl, h0, c0, g_hh, g_c, b_c, hsb);
  // partials[32][128,256] = hs[128,32768] @ W_out[256,32768]^T  (k-split 32)
  k_gemm_tn<<<dim3(2, 4, 32), 256, 0, stream>>>(hsb, W_out, part, 32768, 16, 256, 32768);
  k_reduce<<<128, 256, 0, stream>>>(part, b_out, out);
}

// Round 9
// 715.130 us; speedup vs baseline: 1.4118x; 1.4118x over previous
//
#include <hip/hip_runtime.h>
#include <cstddef>

// Shapes: B=128, T=256, H=128, 4H=512, D=2E=128, GENOME=1e6, OUT*T=256
// d_out: out[128][256] (32768 f32) then emb[128][256][128] (4194304 f32)
// ws (floats): xg @0 (16777216) | hs @16777216 (4194304) | wf_hi @20971520 (32768)
//              | wf_lo @21004288 (32768) | partials @21037056 (1048576)

typedef __attribute__((ext_vector_type(8))) _Float16 f16x8;
typedef __attribute__((ext_vector_type(4))) float f32x4;

__device__ __forceinline__ float frcp(float x) { return __builtin_amdgcn_rcpf(x); }
__device__ __forceinline__ float sigm(float x) { return frcp(1.0f + __expf(-x)); }
__device__ __forceinline__ float ftanh(float x) {
  float e = __expf(2.0f * x);
  return (e - 1.0f) * frcp(e + 1.0f);
}
// split x into fp16 hi + fp16 lo (lo pre-scaled by 2^11)
__device__ __forceinline__ void split2(float x, unsigned short& hi, unsigned short& lo) {
  _Float16 h = (_Float16)x;
  _Float16 l = (_Float16)((x - (float)h) * 2048.0f);
  hi = *(unsigned short*)&h;
  lo = *(unsigned short*)&l;
}
// LDS-only barrier: does NOT drain vmcnt
__device__ __forceinline__ void barrier_lds() {
  asm volatile("s_waitcnt lgkmcnt(0)\n\ts_barrier" ::: "memory");
}

#define SEL4(v, jj) ((jj) == 0 ? (v)[0] : (jj) == 1 ? (v)[1] : (jj) == 2 ? (v)[2] : (v)[3])
#define MFMA16(a, b, c) __builtin_amdgcn_mfma_f32_16x16x32_f16((a), (b), (c), 0, 0, 0)

// ---------- embedding gather ----------
__global__ void k_embed(const int* __restrict__ idx, const float4* __restrict__ table4,
                        float4* __restrict__ emb4) {
  int i = blockIdx.x * blockDim.x + threadIdx.x;   // B*T*2*16 = 1,048,576
  int p = i >> 4, j = i & 15;
  int id = idx[p];
  emb4[(size_t)p * 16 + j] = table4[(size_t)id * 16 + j];
}

// ---------- generic C[M,N] = A[M,K] @ B[N,K]^T, 64x64 tile ----------
__global__ __launch_bounds__(256) void k_gemm_tn(
    const float* __restrict__ A, const float* __restrict__ Bm, float* __restrict__ C,
    int K, int kchunks, int N, size_t partstride)
{
  __shared__ float As[64][65];
  __shared__ float Bs[64][68];
  const int tid = threadIdx.x;
  const int tx = tid & 15, ty = tid >> 4;
  const int m0 = blockIdx.x * 64, n0 = blockIdx.y * 64;
  float acc[4][4] = {};
  size_t kbase = (size_t)blockIdx.z * kchunks * 64;
  for (int kc = 0; kc < kchunks; ++kc) {
    size_t k0 = kbase + (size_t)kc * 64;
    #pragma unroll
    for (int it = 0; it < 4; ++it) {
      int fi = it * 256 + tid;
      int row = fi >> 4, col4 = fi & 15;
      float4 va = *(const float4*)(A + (size_t)(m0 + row) * K + k0 + col4 * 4);
      As[row][col4*4+0] = va.x; As[row][col4*4+1] = va.y;
      As[row][col4*4+2] = va.z; As[row][col4*4+3] = va.w;
      float4 vb = *(const float4*)(Bm + (size_t)(n0 + row) * K + k0 + col4 * 4);
      Bs[col4*4+0][row] = vb.x; Bs[col4*4+1][row] = vb.y;
      Bs[col4*4+2][row] = vb.z; Bs[col4*4+3][row] = vb.w;
    }
    __syncthreads();
    #pragma unroll 8
    for (int k = 0; k < 64; ++k) {
      float a0 = As[ty*4+0][k], a1 = As[ty*4+1][k], a2 = As[ty*4+2][k], a3 = As[ty*4+3][k];
      float b0 = Bs[k][tx*4+0], b1 = Bs[k][tx*4+1], b2 = Bs[k][tx*4+2], b3 = Bs[k][tx*4+3];
      acc[0][0] += a0*b0; acc[0][1] += a0*b1; acc[0][2] += a0*b2; acc[0][3] += a0*b3;
      acc[1][0] += a1*b0; acc[1][1] += a1*b1; acc[1][2] += a1*b2; acc[1][3] += a1*b3;
      acc[2][0] += a2*b0; acc[2][1] += a2*b1; acc[2][2] += a2*b2; acc[2][3] += a2*b3;
      acc[3][0] += a3*b0; acc[3][1] += a3*b1; acc[3][2] += a3*b2; acc[3][3] += a3*b3;
    }
    __syncthreads();
  }
  float* Cp = C + (size_t)blockIdx.z * partstride;
  #pragma unroll
  for (int i = 0; i < 4; ++i) {
    float4 v = make_float4(acc[i][0], acc[i][1], acc[i][2], acc[i][3]);
    *(float4*)(Cp + (size_t)(m0 + ty*4 + i) * N + n0 + tx*4) = v;
  }
}

// ---------- xg := LN(xg)*g_ih + (b_ih + b_hh), in place ----------
__global__ __launch_bounds__(256) void k_xln(float4* __restrict__ xg4,
                                             const float4* __restrict__ g4,
                                             const float4* __restrict__ bi4,
                                             const float4* __restrict__ bh4) {
  int row = blockIdx.x * 4 + (threadIdx.x >> 6);   // 32768 rows
  int lane = threadIdx.x & 63;
  float4* r = xg4 + (size_t)row * 128;
  float4 a = r[lane], b = r[lane + 64];
  float s = a.x + a.y + a.z + a.w + b.x + b.y + b.z + b.w;
  float q = a.x*a.x + a.y*a.y + a.z*a.z + a.w*a.w + b.x*b.x + b.y*b.y + b.z*b.z + b.w*b.w;
  #pragma unroll
  for (int off = 32; off; off >>= 1) { s += __shfl_xor(s, off); q += __shfl_xor(q, off); }
  float m = s * (1.0f / 512.0f);
  float rs = rsqrtf(q * (1.0f / 512.0f) - m * m + 1e-5f);
  float4 ga = g4[lane], gb = g4[64 + lane];
  float4 ia = bi4[lane], ib = bi4[64 + lane];
  float4 ha = bh4[lane], hb = bh4[64 + lane];
  a.x = (a.x - m) * rs * ga.x + ia.x + ha.x; a.y = (a.y - m) * rs * ga.y + ia.y + ha.y;
  a.z = (a.z - m) * rs * ga.z + ia.z + ha.z; a.w = (a.w - m) * rs * ga.w + ia.w + ha.w;
  b.x = (b.x - m) * rs * gb.x + ib.x + hb.x; b.y = (b.y - m) * rs * gb.y + ib.y + hb.y;
  b.z = (b.z - m) * rs * gb.z + ib.z + hb.z; b.w = (b.w - m) * rs * gb.w + ib.w + hb.w;
  r[lane] = a; r[lane + 64] = b;
}

// ---------- W_hh -> dual fp16 A-fragments (hi + scaled lo), k = kc*32+8*(l>>4)+i ----------
__global__ void k_wprep(const float* __restrict__ Whh, uint4* __restrict__ wfh,
                        uint4* __restrict__ wfl) {
  int i = blockIdx.x * 256 + threadIdx.x;  // 8192 = 32*4*64
  int l = i & 63, kc = (i >> 6) & 3, mt = i >> 8;
  int row = mt * 16 + (l & 15);
  int kb = kc * 32 + 8 * (l >> 4);
  float4 a = *(const float4*)(Whh + row * 128 + kb);
  float4 c = *(const float4*)(Whh + row * 128 + kb + 4);
  unsigned short h0,h1,h2,h3,h4,h5,h6,h7, l0,l1,l2,l3,l4,l5,l6,l7;
  split2(a.x,h0,l0); split2(a.y,h1,l1); split2(a.z,h2,l2); split2(a.w,h3,l3);
  split2(c.x,h4,l4); split2(c.y,h5,l5); split2(c.z,h6,l6); split2(c.w,h7,l7);
  uint4 oh, ol;
  oh.x = h0 | ((unsigned)h1 << 16); oh.y = h2 | ((unsigned)h3 << 16);
  oh.z = h4 | ((unsigned)h5 << 16); oh.w = h6 | ((unsigned)h7 << 16);
  ol.x = l0 | ((unsigned)l1 << 16); ol.y = l2 | ((unsigned)l3 << 16);
  ol.z = l4 | ((unsigned)l5 << 16); ol.w = l6 | ((unsigned)l7 << 16);
  wfh[i] = oh; wfl[i] = ol;
}

// ---------- MFMA LSTM scan: 1 row/block, 4 waves (1/SIMD), W dual-fp16 fully
// register-resident (256 VGPR/thread). 2 barriers/step. Wave w owns tiles
// {w, w+4} per gate (i/f/g/o at +0/+8/+16/+24). ----------
__global__ __launch_bounds__(256, 1) void k_scan(
    const float* __restrict__ xln,   // [B][T][512]  (LN(x)*g_ih + b_ih + b_hh)
    const f16x8* __restrict__ wfh,   // [32][4][64] A-frags f16 hi
    const f16x8* __restrict__ wfl,   // [32][4][64] A-frags f16 lo (x2048)
    const float* __restrict__ h0, const float* __restrict__ c0,
    const float* __restrict__ g_hh,
    const float* __restrict__ g_c,  const float* __restrict__ b_c,
    float* __restrict__ hs)          // [B][T][128]
{
  const int b = blockIdx.x;
  const int tid = threadIdx.x;
  const int w = tid >> 6, l = tid & 63;
  const int lg = l >> 4;
  const int col = l & 15;
  const int msel = (col >> 2) & 1;       // 0: tile w, 1: tile w+4 (cols 8-15 mirror)
  const int j = col & 3;
  const bool own = col < 8;              // owner lanes: 1 unit each (32 units/wave)
  const int u = ((w + 4 * msel) << 4) + 4 * lg + j;   // owned hidden unit
  const float inv2048 = 1.0f / 2048.0f;

  __shared__ alignas(16) unsigned short hwh[4][128];  // per-wave private h hi
  __shared__ alignas(16) unsigned short hwl[4][128];  // per-wave private h lo (x2048)
  __shared__ alignas(16) float2 cbuf[128];            // (c_new, o_preact) per unit
  __shared__ alignas(16) float2 hred[4];              // per-wave LN-h partials
  __shared__ alignas(16) float2 cstat[4];             // per-wave c partials

  // ---- W fragments, fully resident (8 tiles x 4 kc x hi/lo = 256 VGPRs) ----
  f16x8 HI0[4], HI1[4], HF0[4], HF1[4], HG0[4], HG1[4], HO0[4], HO1[4];
  f16x8 LI0[4], LI1[4], LF0[4], LF1[4], LG0[4], LG1[4], LO0[4], LO1[4];
  #pragma unroll
  for (int kc = 0; kc < 4; ++kc) {
    HI0[kc] = wfh[((w     ) * 4 + kc) * 64 + l];
    HI1[kc] = wfh[((w +  4) * 4 + kc) * 64 + l];
    HF0[kc] = wfh[((w +  8) * 4 + kc) * 64 + l];
    HF1[kc] = wfh[((w + 12) * 4 + kc) * 64 + l];
    HG0[kc] = wfh[((w + 16) * 4 + kc) * 64 + l];
    HG1[kc] = wfh[((w + 20) * 4 + kc) * 64 + l];
    HO0[kc] = wfh[((w + 24) * 4 + kc) * 64 + l];
    HO1[kc] = wfh[((w + 28) * 4 + kc) * 64 + l];
    LI0[kc] = wfl[((w     ) * 4 + kc) * 64 + l];
    LI1[kc] = wfl[((w +  4) * 4 + kc) * 64 + l];
    LF0[kc] = wfl[((w +  8) * 4 + kc) * 64 + l];
    LF1[kc] = wfl[((w + 12) * 4 + kc) * 64 + l];
    LG0[kc] = wfl[((w + 16) * 4 + kc) * 64 + l];
    LG1[kc] = wfl[((w + 20) * 4 + kc) * 64 + l];
    LO0[kc] = wfl[((w + 24) * 4 + kc) * 64 + l];
    LO1[kc] = wfl[((w + 28) * 4 + kc) * 64 + l];
  }

  // owner params
  const float ghI = g_hh[u], ghF = g_hh[128 + u], ghG = g_hh[256 + u], ghO = g_hh[384 + u];
  float cv = c0[b * 128 + u];
  // finish params (units 2l, 2l+1)
  const float gcA = g_c[2*l], gcB = g_c[2*l+1], bcA = b_c[2*l], bcB = b_c[2*l+1];

  // init own private h copy (units 2l, 2l+1) — wave-local, no barrier needed
  {
    float2 h2 = *(const float2*)(h0 + b * 128 + 2 * l);
    unsigned short a_, b_, c_, d_;
    split2(h2.x, a_, b_); split2(h2.y, c_, d_);
    *(unsigned int*)&hwh[w][2*l] = (unsigned)a_ | ((unsigned)c_ << 16);
    *(unsigned int*)&hwl[w][2*l] = (unsigned)b_ | ((unsigned)d_ << 16);
  }

  const float* xgb = xln + (size_t)b * 131072;
  float* hsb = hs + (size_t)b * 32768;

  // x prefetch for t=0 (owner's unit)
  float xI = xgb[u], xF = xgb[128 + u], xG = xgb[256 + u], xO = xgb[384 + u];

  for (int t = 0; t < 256; ++t) {
    // ---- phase 1: MFMA matvec (own wave's h copy; B-frag = 16B broadcast) ----
    asm volatile("s_waitcnt lgkmcnt(0)" ::: "memory");  // own h writes visible
    f32x4 aI0 = {0,0,0,0}, aI1 = {0,0,0,0}, aF0 = {0,0,0,0}, aF1 = {0,0,0,0};
    f32x4 aG0 = {0,0,0,0}, aG1 = {0,0,0,0}, aO0 = {0,0,0,0}, aO1 = {0,0,0,0};
    f32x4 eI0 = {0,0,0,0}, eI1 = {0,0,0,0}, eF0 = {0,0,0,0}, eF1 = {0,0,0,0};
    f32x4 eG0 = {0,0,0,0}, eG1 = {0,0,0,0}, eO0 = {0,0,0,0}, eO1 = {0,0,0,0};
    #pragma unroll
    for (int kc = 0; kc < 4; ++kc) {
      f16x8 bh = *(const f16x8*)((const char*)&hwh[w][0] + kc * 64 + 16 * lg);
      f16x8 bl = *(const f16x8*)((const char*)&hwl[w][0] + kc * 64 + 16 * lg);
      aI0 = MFMA16(HI0[kc], bh, aI0); eI0 = MFMA16(HI0[kc], bl, eI0); eI0 = MFMA16(LI0[kc], bh, eI0);
      aI1 = MFMA16(HI1[kc], bh, aI1); eI1 = MFMA16(HI1[kc], bl, eI1); eI1 = MFMA16(LI1[kc], bh, eI1);
      aF0 = MFMA16(HF0[kc], bh, aF0); eF0 = MFMA16(HF0[kc], bl, eF0); eF0 = MFMA16(LF0[kc], bh, eF0);
      aF1 = MFMA16(HF1[kc], bh, aF1); eF1 = MFMA16(HF1[kc], bl, eF1); eF1 = MFMA16(LF1[kc], bh, eF1);
      aG0 = MFMA16(HG0[kc], bh, aG0); eG0 = MFMA16(HG0[kc], bl, eG0); eG0 = MFMA16(LG0[kc], bh, eG0);
      aG1 = MFMA16(HG1[kc], bh, aG1); eG1 = MFMA16(HG1[kc], bl, eG1); eG1 = MFMA16(LG1[kc], bh, eG1);
      aO0 = MFMA16(HO0[kc], bh, aO0); eO0 = MFMA16(HO0[kc], bl, eO0); eO0 = MFMA16(LO0[kc], bh, eO0);
      aO1 = MFMA16(HO1[kc], bh, aO1); eO1 = MFMA16(HO1[kc], bl, eO1); eO1 = MFMA16(LO1[kc], bh, eO1);
    }
    aI0 += eI0 * inv2048; aI1 += eI1 * inv2048;
    aF0 += eF0 * inv2048; aF1 += eF1 * inv2048;
    aG0 += eG0 * inv2048; aG1 += eG1 * inv2048;
    aO0 += eO0 * inv2048; aO1 += eO1 * inv2048;

    // ---- phase 2: LN-h stats (this wave's 128 gate rows; cols are duplicates) ----
    f32x4 sv = ((aI0 + aI1) + (aF0 + aF1)) + ((aG0 + aG1) + (aO0 + aO1));
    f32x4 qv = ((aI0*aI0 + aI1*aI1) + (aF0*aF0 + aF1*aF1)) +
               ((aG0*aG0 + aG1*aG1) + (aO0*aO0 + aO1*aO1));
    float s = (sv[0] + sv[1]) + (sv[2] + sv[3]);
    float q = (qv[0] + qv[1]) + (qv[2] + qv[3]);
    s += __shfl_xor(s, 16); s += __shfl_xor(s, 32);
    q += __shfl_xor(q, 16); q += __shfl_xor(q, 32);
    if (l == 0) hred[w] = make_float2(s, q);

    barrier_lds();                      // B1

    // ---- phase 3: gates + c for owner's unit ----
    float4 hp0 = *(const float4*)&hred[0];   // (s0,q0,s1,q1)
    float4 hp1 = *(const float4*)&hred[2];
    float mh = ((hp0.x + hp0.z) + (hp1.x + hp1.z)) * (1.0f / 512.0f);
    float vq = ((hp0.y + hp0.w) + (hp1.y + hp1.w)) * (1.0f / 512.0f) - mh * mh;
    float rh = rsqrtf(vq + 1e-5f);

    float aIv = msel ? SEL4(aI1, j) : SEL4(aI0, j);
    float aFv = msel ? SEL4(aF1, j) : SEL4(aF0, j);
    float aGv = msel ? SEL4(aG1, j) : SEL4(aG0, j);
    float aOv = msel ? SEL4(aO1, j) : SEL4(aO0, j);

    float gI = xI + (aIv - mh) * rh * ghI;
    float gF = xF + (aFv - mh) * rh * ghF;
    float gG = xG + (aGv - mh) * rh * ghG;
    float gO = xO + (aOv - mh) * rh * ghO;

    float cn = sigm(gF) * cv + sigm(gI) * ftanh(gG);
    cv = cn;

    float cs = own ? cn : 0.f, cq = own ? cn * cn : 0.f;
    cs += __shfl_xor(cs, 1); cq += __shfl_xor(cq, 1);
    cs += __shfl_xor(cs, 2); cq += __shfl_xor(cq, 2);
    cs += __shfl_xor(cs, 4); cq += __shfl_xor(cq, 4);
    cs += __shfl_xor(cs, 16); cq += __shfl_xor(cq, 16);
    cs += __shfl_xor(cs, 32); cq += __shfl_xor(cq, 32);
    if (l == 0) cstat[w] = make_float2(cs, cq);
    if (own) cbuf[u] = make_float2(cn, gO);

    barrier_lds();                      // B2

    // ---- phase 4: every wave finishes units 2l, 2l+1 into its own h copy ----
    float4 cp0 = *(const float4*)&cstat[0];
    float4 cp1 = *(const float4*)&cstat[2];
    float mc = ((cp0.x + cp0.z) + (cp1.x + cp1.z)) * (1.0f / 128.0f);
    float vc = ((cp0.y + cp0.w) + (cp1.y + cp1.w)) * (1.0f / 128.0f) - mc * mc;
    float rc = rsqrtf(vc + 1e-5f);

    float4 cb = *(const float4*)&cbuf[2 * l];   // (cn0, gO0, cn1, gO1)
    float hn0 = sigm(cb.y) * ftanh((cb.x - mc) * rc * gcA + bcA);
    float hn1 = sigm(cb.w) * ftanh((cb.z - mc) * rc * gcB + bcB);

    {
      unsigned short a_, b_, c_, d_;
      split2(hn0, a_, b_); split2(hn1, c_, d_);
      *(unsigned int*)&hwh[w][2*l] = (unsigned)a_ | ((unsigned)c_ << 16);
      *(unsigned int*)&hwl[w][2*l] = (unsigned)b_ | ((unsigned)d_ << 16);
    }
    if (w == 0) *(float2*)(hsb + (size_t)t * 128 + 2 * l) = make_float2(hn0, hn1);

    // prefetch next step's x (consumed after next B1 — long slack)
    const float* xn = xgb + (size_t)((t + 1) & 255) * 512;
    xI = xn[u]; xF = xn[128 + u]; xG = xn[256 + u]; xO = xn[384 + u];
  }
}

// ---------- k-split reduce + bias + sigmoid ----------
__global__ void k_reduce(const float* __restrict__ part, const float* __restrict__ b_out,
                         float* __restrict__ out) {
  int i = blockIdx.x * 256 + threadIdx.x;   // 0..32767 = b*256+o
  float s = b_out[i & 255];
  #pragma unroll
  for (int z = 0; z < 32; ++z) s += part[(size_t)z * 32768 + i];
  out[i] = sigm(s);
}

extern "C" void kernel_launch(void* const* d_in, const int* in_sizes, int n_in,
                              void* d_out, int out_size, void* d_ws, size_t ws_size,
                              hipStream_t stream) {
  const int*   idx   = (const int*)  d_in[0];
  const float* h0    = (const float*)d_in[1];
  const float* c0    = (const float*)d_in[2];
  const float* table = (const float*)d_in[3];
  const float* W_ih  = (const float*)d_in[4];
  const float* W_hh  = (const float*)d_in[5];
  const float* g_ih  = (const float*)d_in[6];
  const float* b_ih  = (const float*)d_in[7];
  const float* g_hh  = (const float*)d_in[8];
  const float* b_hh  = (const float*)d_in[9];
  const float* g_c   = (const float*)d_in[10];
  const float* b_c   = (const float*)d_in[11];
  const float* W_out = (const float*)d_in[12];
  const float* b_out = (const float*)d_in[13];

  float* out  = (float*)d_out;             // 32768
  float* emb  = out + 32768;               // 4194304 (output #2)
  float* ws   = (float*)d_ws;
  float* xg   = ws;                        // 16777216 floats (becomes xln in place)
  float* hsb  = ws + 16777216;             // 4194304
  uint4* wfh  = (uint4*)(ws + 20971520);   // 8192 uint4 (128 KB)
  uint4* wfl  = (uint4*)(ws + 21004288);   // 8192 uint4 (128 KB)
  float* part = ws + 21037056;             // 1048576

  k_embed<<<4096, 256, 0, stream>>>(idx, (const float4*)table, (float4*)emb);
  // x_gates[32768,512] = emb[32768,128] @ W_ih[512,128]^T
  k_gemm_tn<<<dim3(512, 8, 1), 256, 0, stream>>>(emb, W_ih, xg, 128, 2, 512, 0);
  k_xln<<<8192, 256, 0, stream>>>((float4*)xg, (const float4*)g_ih,
                                  (const float4*)b_ih, (const float4*)b_hh);
  k_wprep<<<32, 256, 0, stream>>>(W_hh, wfh, wfl);
  k_scan<<<128, 256, 0, stream>>>(xg, (const f16x8*)wfh, (const f16x8*)wfl,
                                  h0, c0, g_hh, g_c, b_c, hsb);
  // partials[32][128,256] = hs[128,32768] @ W_out[256,32768]^T  (k-split 32)
  k_gemm_tn<<<dim3(2, 4, 32), 256, 0, stream>>>(hsb, W_out, part, 32768, 16, 256, 32768);
  k_reduce<<<128, 256, 0, stream>>>(part, b_out, out);
}

// Round 10
// 671.236 us; speedup vs baseline: 1.5041x; 1.0654x over previous
//
#include <hip/hip_runtime.h>
#include <cstddef>

// Shapes: B=128, T=256, H=128, 4H=512, D=2E=128, GENOME=1e6, OUT*T=256
// d_out: out[128][256] (32768 f32) then emb[128][256][128] (4194304 f32)
// ws (floats): xg @0 (16777216) | hs @16777216 (4194304) | wf_hi @20971520 (32768)
//              | wf_lo @21004288 (32768) | partials @21037056 (1048576)

typedef __attribute__((ext_vector_type(8))) _Float16 f16x8;
typedef __attribute__((ext_vector_type(4))) float f32x4;

__device__ __forceinline__ float frcp(float x) { return __builtin_amdgcn_rcpf(x); }
__device__ __forceinline__ float sigm(float x) { return frcp(1.0f + __expf(-x)); }
__device__ __forceinline__ float ftanh(float x) {
  float e = __expf(2.0f * x);
  return (e - 1.0f) * frcp(e + 1.0f);
}
// split x into fp16 hi + fp16 lo (lo pre-scaled by 2^11)
__device__ __forceinline__ void split2(float x, unsigned short& hi, unsigned short& lo) {
  _Float16 h = (_Float16)x;
  _Float16 l = (_Float16)((x - (float)h) * 2048.0f);
  hi = *(unsigned short*)&h;
  lo = *(unsigned short*)&l;
}
// LDS-only barrier: does NOT drain vmcnt
__device__ __forceinline__ void barrier_lds() {
  asm volatile("s_waitcnt lgkmcnt(0)\n\ts_barrier" ::: "memory");
}

#define SEL4(v, jj) ((jj) == 0 ? (v)[0] : (jj) == 1 ? (v)[1] : (jj) == 2 ? (v)[2] : (v)[3])
#define MFMA16(a, b, c) __builtin_amdgcn_mfma_f32_16x16x32_f16((a), (b), (c), 0, 0, 0)
// pin a 4-element f16x8 array into AGPRs; asm results are NOT rematerializable
#define PIN_A4(X) asm volatile("" : "+a"(X[0]), "+a"(X[1]), "+a"(X[2]), "+a"(X[3]))

// ---------- embedding gather ----------
__global__ void k_embed(const int* __restrict__ idx, const float4* __restrict__ table4,
                        float4* __restrict__ emb4) {
  int i = blockIdx.x * blockDim.x + threadIdx.x;   // B*T*2*16 = 1,048,576
  int p = i >> 4, j = i & 15;
  int id = idx[p];
  emb4[(size_t)p * 16 + j] = table4[(size_t)id * 16 + j];
}

// ---------- generic C[M,N] = A[M,K] @ B[N,K]^T, 64x64 tile ----------
__global__ __launch_bounds__(256) void k_gemm_tn(
    const float* __restrict__ A, const float* __restrict__ Bm, float* __restrict__ C,
    int K, int kchunks, int N, size_t partstride)
{
  __shared__ float As[64][65];
  __shared__ float Bs[64][68];
  const int tid = threadIdx.x;
  const int tx = tid & 15, ty = tid >> 4;
  const int m0 = blockIdx.x * 64, n0 = blockIdx.y * 64;
  float acc[4][4] = {};
  size_t kbase = (size_t)blockIdx.z * kchunks * 64;
  for (int kc = 0; kc < kchunks; ++kc) {
    size_t k0 = kbase + (size_t)kc * 64;
    #pragma unroll
    for (int it = 0; it < 4; ++it) {
      int fi = it * 256 + tid;
      int row = fi >> 4, col4 = fi & 15;
      float4 va = *(const float4*)(A + (size_t)(m0 + row) * K + k0 + col4 * 4);
      As[row][col4*4+0] = va.x; As[row][col4*4+1] = va.y;
      As[row][col4*4+2] = va.z; As[row][col4*4+3] = va.w;
      float4 vb = *(const float4*)(Bm + (size_t)(n0 + row) * K + k0 + col4 * 4);
      Bs[col4*4+0][row] = vb.x; Bs[col4*4+1][row] = vb.y;
      Bs[col4*4+2][row] = vb.z; Bs[col4*4+3][row] = vb.w;
    }
    __syncthreads();
    #pragma unroll 8
    for (int k = 0; k < 64; ++k) {
      float a0 = As[ty*4+0][k], a1 = As[ty*4+1][k], a2 = As[ty*4+2][k], a3 = As[ty*4+3][k];
      float b0 = Bs[k][tx*4+0], b1 = Bs[k][tx*4+1], b2 = Bs[k][tx*4+2], b3 = Bs[k][tx*4+3];
      acc[0][0] += a0*b0; acc[0][1] += a0*b1; acc[0][2] += a0*b2; acc[0][3] += a0*b3;
      acc[1][0] += a1*b0; acc[1][1] += a1*b1; acc[1][2] += a1*b2; acc[1][3] += a1*b3;
      acc[2][0] += a2*b0; acc[2][1] += a2*b1; acc[2][2] += a2*b2; acc[2][3] += a2*b3;
      acc[3][0] += a3*b0; acc[3][1] += a3*b1; acc[3][2] += a3*b2; acc[3][3] += a3*b3;
    }
    __syncthreads();
  }
  float* Cp = C + (size_t)blockIdx.z * partstride;
  #pragma unroll
  for (int i = 0; i < 4; ++i) {
    float4 v = make_float4(acc[i][0], acc[i][1], acc[i][2], acc[i][3]);
    *(float4*)(Cp + (size_t)(m0 + ty*4 + i) * N + n0 + tx*4) = v;
  }
}

// ---------- xg := LN(xg)*g_ih + (b_ih + b_hh), in place ----------
__global__ __launch_bounds__(256) void k_xln(float4* __restrict__ xg4,
                                             const float4* __restrict__ g4,
                                             const float4* __restrict__ bi4,
                                             const float4* __restrict__ bh4) {
  int row = blockIdx.x * 4 + (threadIdx.x >> 6);   // 32768 rows
  int lane = threadIdx.x & 63;
  float4* r = xg4 + (size_t)row * 128;
  float4 a = r[lane], b = r[lane + 64];
  float s = a.x + a.y + a.z + a.w + b.x + b.y + b.z + b.w;
  float q = a.x*a.x + a.y*a.y + a.z*a.z + a.w*a.w + b.x*b.x + b.y*b.y + b.z*b.z + b.w*b.w;
  #pragma unroll
  for (int off = 32; off; off >>= 1) { s += __shfl_xor(s, off); q += __shfl_xor(q, off); }
  float m = s * (1.0f / 512.0f);
  float rs = rsqrtf(q * (1.0f / 512.0f) - m * m + 1e-5f);
  float4 ga = g4[lane], gb = g4[64 + lane];
  float4 ia = bi4[lane], ib = bi4[64 + lane];
  float4 ha = bh4[lane], hb = bh4[64 + lane];
  a.x = (a.x - m) * rs * ga.x + ia.x + ha.x; a.y = (a.y - m) * rs * ga.y + ia.y + ha.y;
  a.z = (a.z - m) * rs * ga.z + ia.z + ha.z; a.w = (a.w - m) * rs * ga.w + ia.w + ha.w;
  b.x = (b.x - m) * rs * gb.x + ib.x + hb.x; b.y = (b.y - m) * rs * gb.y + ib.y + hb.y;
  b.z = (b.z - m) * rs * gb.z + ib.z + hb.z; b.w = (b.w - m) * rs * gb.w + ib.w + hb.w;
  r[lane] = a; r[lane + 64] = b;
}

// ---------- W_hh -> dual fp16 A-fragments (hi + scaled lo), k = kc*32+8*(l>>4)+i ----------
__global__ void k_wprep(const float* __restrict__ Whh, uint4* __restrict__ wfh,
                        uint4* __restrict__ wfl) {
  int i = blockIdx.x * 256 + threadIdx.x;  // 8192 = 32*4*64
  int l = i & 63, kc = (i >> 6) & 3, mt = i >> 8;
  int row = mt * 16 + (l & 15);
  int kb = kc * 32 + 8 * (l >> 4);
  float4 a = *(const float4*)(Whh + row * 128 + kb);
  float4 c = *(const float4*)(Whh + row * 128 + kb + 4);
  unsigned short h0,h1,h2,h3,h4,h5,h6,h7, l0,l1,l2,l3,l4,l5,l6,l7;
  split2(a.x,h0,l0); split2(a.y,h1,l1); split2(a.z,h2,l2); split2(a.w,h3,l3);
  split2(c.x,h4,l4); split2(c.y,h5,l5); split2(c.z,h6,l6); split2(c.w,h7,l7);
  uint4 oh, ol;
  oh.x = h0 | ((unsigned)h1 << 16); oh.y = h2 | ((unsigned)h3 << 16);
  oh.z = h4 | ((unsigned)h5 << 16); oh.w = h6 | ((unsigned)h7 << 16);
  ol.x = l0 | ((unsigned)l1 << 16); ol.y = l2 | ((unsigned)l3 << 16);
  ol.z = l4 | ((unsigned)l5 << 16); ol.w = l6 | ((unsigned)l7 << 16);
  wfh[i] = oh; wfl[i] = ol;
}

// ---------- MFMA LSTM scan: 1 row/block, 4 waves (1/SIMD). W dual-fp16 PINNED IN
// AGPRS (256 AGPRs/thread; asm results can't be rematerialized -> zero W refetch).
// 2 barriers/step. Wave w owns tiles {w, w+4} per gate (i/f/g/o at +0/+8/+16/+24).
__global__ __launch_bounds__(256, 1) void k_scan(
    const float* __restrict__ xln,   // [B][T][512]  (LN(x)*g_ih + b_ih + b_hh)
    const f16x8* __restrict__ wfh,   // [32][4][64] A-frags f16 hi
    const f16x8* __restrict__ wfl,   // [32][4][64] A-frags f16 lo (x2048)
    const float* __restrict__ h0, const float* __restrict__ c0,
    const float* __restrict__ g_hh,
    const float* __restrict__ g_c,  const float* __restrict__ b_c,
    float* __restrict__ hs)          // [B][T][128]
{
  const int b = blockIdx.x;
  const int tid = threadIdx.x;
  const int w = tid >> 6, l = tid & 63;
  const int lg = l >> 4;
  const int col = l & 15;
  const int msel = (col >> 2) & 1;       // 0: tile w, 1: tile w+4 (cols 8-15 mirror)
  const int j = col & 3;
  const bool own = col < 8;              // owner lanes: 1 unit each (32 units/wave)
  const int u = ((w + 4 * msel) << 4) + 4 * lg + j;   // owned hidden unit
  const float inv2048 = 1.0f / 2048.0f;

  __shared__ alignas(16) unsigned short hwh[4][128];  // per-wave private h hi
  __shared__ alignas(16) unsigned short hwl[4][128];  // per-wave private h lo (x2048)
  __shared__ alignas(16) float2 cbuf[128];            // (c_new, o_preact) per unit
  __shared__ alignas(16) float2 hred[4];              // per-wave LN-h partials
  __shared__ alignas(16) float2 cstat[4];             // per-wave c partials

  // ---- W fragments: load once, pin in AGPRs ----
  f16x8 HI0[4], HI1[4], HF0[4], HF1[4], HG0[4], HG1[4], HO0[4], HO1[4];
  f16x8 LI0[4], LI1[4], LF0[4], LF1[4], LG0[4], LG1[4], LO0[4], LO1[4];
  #pragma unroll
  for (int kc = 0; kc < 4; ++kc) {
    HI0[kc] = wfh[((w     ) * 4 + kc) * 64 + l];
    HI1[kc] = wfh[((w +  4) * 4 + kc) * 64 + l];
    HF0[kc] = wfh[((w +  8) * 4 + kc) * 64 + l];
    HF1[kc] = wfh[((w + 12) * 4 + kc) * 64 + l];
    HG0[kc] = wfh[((w + 16) * 4 + kc) * 64 + l];
    HG1[kc] = wfh[((w + 20) * 4 + kc) * 64 + l];
    HO0[kc] = wfh[((w + 24) * 4 + kc) * 64 + l];
    HO1[kc] = wfh[((w + 28) * 4 + kc) * 64 + l];
    LI0[kc] = wfl[((w     ) * 4 + kc) * 64 + l];
    LI1[kc] = wfl[((w +  4) * 4 + kc) * 64 + l];
    LF0[kc] = wfl[((w +  8) * 4 + kc) * 64 + l];
    LF1[kc] = wfl[((w + 12) * 4 + kc) * 64 + l];
    LG0[kc] = wfl[((w + 16) * 4 + kc) * 64 + l];
    LG1[kc] = wfl[((w + 20) * 4 + kc) * 64 + l];
    LO0[kc] = wfl[((w + 24) * 4 + kc) * 64 + l];
    LO1[kc] = wfl[((w + 28) * 4 + kc) * 64 + l];
  }
  PIN_A4(HI0); PIN_A4(HI1); PIN_A4(HF0); PIN_A4(HF1);
  PIN_A4(HG0); PIN_A4(HG1); PIN_A4(HO0); PIN_A4(HO1);
  PIN_A4(LI0); PIN_A4(LI1); PIN_A4(LF0); PIN_A4(LF1);
  PIN_A4(LG0); PIN_A4(LG1); PIN_A4(LO0); PIN_A4(LO1);

  // owner params
  const float ghI = g_hh[u], ghF = g_hh[128 + u], ghG = g_hh[256 + u], ghO = g_hh[384 + u];
  float cv = c0[b * 128 + u];
  // finish params (units 2l, 2l+1)
  const float gcA = g_c[2*l], gcB = g_c[2*l+1], bcA = b_c[2*l], bcB = b_c[2*l+1];

  // init own private h copy (units 2l, 2l+1) — wave-local, no barrier needed
  {
    float2 h2 = *(const float2*)(h0 + b * 128 + 2 * l);
    unsigned short a_, b_, c_, d_;
    split2(h2.x, a_, b_); split2(h2.y, c_, d_);
    *(unsigned int*)&hwh[w][2*l] = (unsigned)a_ | ((unsigned)c_ << 16);
    *(unsigned int*)&hwl[w][2*l] = (unsigned)b_ | ((unsigned)d_ << 16);
  }

  const float* xgb = xln + (size_t)b * 131072;
  float* hsb = hs + (size_t)b * 32768;

  // x prefetch for t=0 (owner's unit)
  float xI = xgb[u], xF = xgb[128 + u], xG = xgb[256 + u], xO = xgb[384 + u];

  for (int t = 0; t < 256; ++t) {
    // ---- phase 1: MFMA matvec (own wave's h copy; B-frag = 16B broadcast) ----
    asm volatile("s_waitcnt lgkmcnt(0)" ::: "memory");  // own h writes visible
    f32x4 aI0 = {0,0,0,0}, aI1 = {0,0,0,0}, aF0 = {0,0,0,0}, aF1 = {0,0,0,0};
    f32x4 aG0 = {0,0,0,0}, aG1 = {0,0,0,0}, aO0 = {0,0,0,0}, aO1 = {0,0,0,0};
    f32x4 eI0 = {0,0,0,0}, eI1 = {0,0,0,0}, eF0 = {0,0,0,0}, eF1 = {0,0,0,0};
    f32x4 eG0 = {0,0,0,0}, eG1 = {0,0,0,0}, eO0 = {0,0,0,0}, eO1 = {0,0,0,0};
    #pragma unroll
    for (int kc = 0; kc < 4; ++kc) {
      f16x8 bh = *(const f16x8*)((const char*)&hwh[w][0] + kc * 64 + 16 * lg);
      f16x8 bl = *(const f16x8*)((const char*)&hwl[w][0] + kc * 64 + 16 * lg);
      aI0 = MFMA16(HI0[kc], bh, aI0); eI0 = MFMA16(HI0[kc], bl, eI0); eI0 = MFMA16(LI0[kc], bh, eI0);
      aI1 = MFMA16(HI1[kc], bh, aI1); eI1 = MFMA16(HI1[kc], bl, eI1); eI1 = MFMA16(LI1[kc], bh, eI1);
      aF0 = MFMA16(HF0[kc], bh, aF0); eF0 = MFMA16(HF0[kc], bl, eF0); eF0 = MFMA16(LF0[kc], bh, eF0);
      aF1 = MFMA16(HF1[kc], bh, aF1); eF1 = MFMA16(HF1[kc], bl, eF1); eF1 = MFMA16(LF1[kc], bh, eF1);
      aG0 = MFMA16(HG0[kc], bh, aG0); eG0 = MFMA16(HG0[kc], bl, eG0); eG0 = MFMA16(LG0[kc], bh, eG0);
      aG1 = MFMA16(HG1[kc], bh, aG1); eG1 = MFMA16(HG1[kc], bl, eG1); eG1 = MFMA16(LG1[kc], bh, eG1);
      aO0 = MFMA16(HO0[kc], bh, aO0); eO0 = MFMA16(HO0[kc], bl, eO0); eO0 = MFMA16(LO0[kc], bh, eO0);
      aO1 = MFMA16(HO1[kc], bh, aO1); eO1 = MFMA16(HO1[kc], bl, eO1); eO1 = MFMA16(LO1[kc], bh, eO1);
    }
    aI0 += eI0 * inv2048; aI1 += eI1 * inv2048;
    aF0 += eF0 * inv2048; aF1 += eF1 * inv2048;
    aG0 += eG0 * inv2048; aG1 += eG1 * inv2048;
    aO0 += eO0 * inv2048; aO1 += eO1 * inv2048;

    // ---- phase 2: LN-h stats (this wave's 128 gate rows; cols are duplicates) ----
    f32x4 sv = ((aI0 + aI1) + (aF0 + aF1)) + ((aG0 + aG1) + (aO0 + aO1));
    f32x4 qv = ((aI0*aI0 + aI1*aI1) + (aF0*aF0 + aF1*aF1)) +
               ((aG0*aG0 + aG1*aG1) + (aO0*aO0 + aO1*aO1));
    float s = (sv[0] + sv[1]) + (sv[2] + sv[3]);
    float q = (qv[0] + qv[1]) + (qv[2] + qv[3]);
    s += __shfl_xor(s, 16); s += __shfl_xor(s, 32);
    q += __shfl_xor(q, 16); q += __shfl_xor(q, 32);
    if (l == 0) hred[w] = make_float2(s, q);

    barrier_lds();                      // B1

    // ---- phase 3: gates + c for owner's unit ----
    float4 hp0 = *(const float4*)&hred[0];   // (s0,q0,s1,q1)
    float4 hp1 = *(const float4*)&hred[2];
    float mh = ((hp0.x + hp0.z) + (hp1.x + hp1.z)) * (1.0f / 512.0f);
    float vq = ((hp0.y + hp0.w) + (hp1.y + hp1.w)) * (1.0f / 512.0f) - mh * mh;
    float rh = rsqrtf(vq + 1e-5f);

    float aIv = msel ? SEL4(aI1, j) : SEL4(aI0, j);
    float aFv = msel ? SEL4(aF1, j) : SEL4(aF0, j);
    float aGv = msel ? SEL4(aG1, j) : SEL4(aG0, j);
    float aOv = msel ? SEL4(aO1, j) : SEL4(aO0, j);

    float gI = xI + (aIv - mh) * rh * ghI;
    float gF = xF + (aFv - mh) * rh * ghF;
    float gG = xG + (aGv - mh) * rh * ghG;
    float gO = xO + (aOv - mh) * rh * ghO;

    float cn = sigm(gF) * cv + sigm(gI) * ftanh(gG);
    cv = cn;

    float cs = own ? cn : 0.f, cq = own ? cn * cn : 0.f;
    cs += __shfl_xor(cs, 1); cq += __shfl_xor(cq, 1);
    cs += __shfl_xor(cs, 2); cq += __shfl_xor(cq, 2);
    cs += __shfl_xor(cs, 4); cq += __shfl_xor(cq, 4);
    cs += __shfl_xor(cs, 16); cq += __shfl_xor(cq, 16);
    cs += __shfl_xor(cs, 32); cq += __shfl_xor(cq, 32);
    if (l == 0) cstat[w] = make_float2(cs, cq);
    if (own) cbuf[u] = make_float2(cn, gO);

    barrier_lds();                      // B2

    // ---- phase 4: every wave finishes units 2l, 2l+1 into its own h copy ----
    float4 cp0 = *(const float4*)&cstat[0];
    float4 cp1 = *(const float4*)&cstat[2];
    float mc = ((cp0.x + cp0.z) + (cp1.x + cp1.z)) * (1.0f / 128.0f);
    float vc = ((cp0.y + cp0.w) + (cp1.y + cp1.w)) * (1.0f / 128.0f) - mc * mc;
    float rc = rsqrtf(vc + 1e-5f);

    float4 cb = *(const float4*)&cbuf[2 * l];   // (cn0, gO0, cn1, gO1)
    float hn0 = sigm(cb.y) * ftanh((cb.x - mc) * rc * gcA + bcA);
    float hn1 = sigm(cb.w) * ftanh((cb.z - mc) * rc * gcB + bcB);

    {
      unsigned short a_, b_, c_, d_;
      split2(hn0, a_, b_); split2(hn1, c_, d_);
      *(unsigned int*)&hwh[w][2*l] = (unsigned)a_ | ((unsigned)c_ << 16);
      *(unsigned int*)&hwl[w][2*l] = (unsigned)b_ | ((unsigned)d_ << 16);
    }
    if (w == 0) *(float2*)(hsb + (size_t)t * 128 + 2 * l) = make_float2(hn0, hn1);

    // prefetch next step's x (consumed after next B1 — long slack)
    const float* xn = xgb + (size_t)((t + 1) & 255) * 512;
    xI = xn[u]; xF = xn[128 + u]; xG = xn[256 + u]; xO = xn[384 + u];
  }
}

// ---------- k-split reduce + bias + sigmoid ----------
__global__ void k_reduce(const float* __restrict__ part, const float* __restrict__ b_out,
                         float* __restrict__ out) {
  int i = blockIdx.x * 256 + threadIdx.x;   // 0..32767 = b*256+o
  float s = b_out[i & 255];
  #pragma unroll
  for (int z = 0; z < 32; ++z) s += part[(size_t)z * 32768 + i];
  out[i] = sigm(s);
}

extern "C" void kernel_launch(void* const* d_in, const int* in_sizes, int n_in,
                              void* d_out, int out_size, void* d_ws, size_t ws_size,
                              hipStream_t stream) {
  const int*   idx   = (const int*)  d_in[0];
  const float* h0    = (const float*)d_in[1];
  const float* c0    = (const float*)d_in[2];
  const float* table = (const float*)d_in[3];
  const float* W_ih  = (const float*)d_in[4];
  const float* W_hh  = (const float*)d_in[5];
  const float* g_ih  = (const float*)d_in[6];
  const float* b_ih  = (const float*)d_in[7];
  const float* g_hh  = (const float*)d_in[8];
  const float* b_hh  = (const float*)d_in[9];
  const float* g_c   = (const float*)d_in[10];
  const float* b_c   = (const float*)d_in[11];
  const float* W_out = (const float*)d_in[12];
  const float* b_out = (const float*)d_in[13];

  float* out  = (float*)d_out;             // 32768
  float* emb  = out + 32768;               // 4194304 (output #2)
  float* ws   = (float*)d_ws;
  float* xg   = ws;                        // 16777216 floats (becomes xln in place)
  float* hsb  = ws + 16777216;             // 4194304
  uint4* wfh  = (uint4*)(ws + 20971520);   // 8192 uint4 (128 KB)
  uint4* wfl  = (uint4*)(ws + 21004288);   // 8192 uint4 (128 KB)
  float* part = ws + 21037056;             // 1048576

  k_embed<<<4096, 256, 0, stream>>>(idx, (const float4*)table, (float4*)emb);
  // x_gates[32768,512] = emb[32768,128] @ W_ih[512,128]^T
  k_gemm_tn<<<dim3(512, 8, 1), 256, 0, stream>>>(emb, W_ih, xg, 128, 2, 512, 0);
  k_xln<<<8192, 256, 0, stream>>>((float4*)xg, (const float4*)g_ih,
                                  (const float4*)b_ih, (const float4*)b_hh);
  k_wprep<<<32, 256, 0, stream>>>(W_hh, wfh, wfl);
  k_scan<<<128, 256, 0, stream>>>(xg, (const f16x8*)wfh, (const f16x8*)wfl,
                                  h0, c0, g_hh, g_c, b_c, hsb);
  // partials[32][128,256] = hs[128,32768] @ W_out[256,32768]^T  (k-split 32)
  k_gemm_tn<<<dim3(2, 4, 32), 256, 0, stream>>>(hsb, W_out, part, 32768, 16, 256, 32768);
  k_reduce<<<128, 256, 0, stream>>>(part, b_out, out);
}